// Round 9
// baseline (241.509 us; speedup 1.0000x reference)
//
#include <hip/hip_runtime.h>
#include <hip/hip_bf16.h>
#include <hip/hip_fp8.h>

// Problem constants
#define Bb 2048
#define Tt 50
#define Vv 65
#define Ee 100
#define Hh 20
#define Dd 5

typedef __bf16 v8bf __attribute__((ext_vector_type(8)));
typedef short v8s __attribute__((ext_vector_type(8)));
typedef short v4s __attribute__((ext_vector_type(4)));
typedef float f32x4 __attribute__((ext_vector_type(4)));

__device__ __forceinline__ v8bf bzero8() {
    v8s z = {0, 0, 0, 0, 0, 0, 0, 0};
    union { v8s s; v8bf b; } u; u.s = z; return u.b;
}
__device__ __forceinline__ unsigned short bfbits(float f) {
    union { __hip_bfloat16 h; unsigned short s; } c;
    c.h = __float2bfloat16(f);
    return c.s;
}
__device__ __forceinline__ float bf2f(short s) {
    union { unsigned i; float f; } c; c.i = ((unsigned)(unsigned short)s) << 16; return c.f;
}
__device__ __forceinline__ unsigned pack2(float a, float b) {
    return (unsigned)bfbits(a) | ((unsigned)bfbits(b) << 16);
}
__device__ __forceinline__ unsigned char f32_to_fp8(float v) {
#if __has_builtin(__builtin_amdgcn_cvt_pk_fp8_f32)
    return (unsigned char)(__builtin_amdgcn_cvt_pk_fp8_f32(v, 0.f, 0, false) & 0xff);
#else
    union { __hip_fp8_e4m3 t; unsigned char c; } u;
    u.t = __hip_fp8_e4m3(v);
    return u.c;
#endif
}

// K=16 bf16 MFMA (validated on HW in R7/R8)
__device__ __forceinline__ f32x4 mfma_16x16x16_bf16(v4s a, v4s b, f32x4 c) {
#if __has_builtin(__builtin_amdgcn_mfma_f32_16x16x16bf16_1k)
    return __builtin_amdgcn_mfma_f32_16x16x16bf16_1k(a, b, c, 0, 0, 0);
#else
    f32x4 d;
    asm volatile("v_mfma_f32_16x16x16_bf16 %0, %1, %2, %3\n\ts_nop 7\n\ts_nop 4"
                 : "=v"(d) : "v"(a), "v"(b), "v"(c));
    return d;
#endif
}

// ws layout (bytes)
#define WS_WKQV 1024                     // [320][128] bf16 (k AND q rows pre-scaled by sqrt(10*log2e))
#define WS_WFF  (1024 + 81920)           // [128][128] bf16
#define WS_WLM  (1024 + 81920 + 32768)   // [80][128] bf16
#define WS_LPART (1024 + 81920 + 32768 + 20480)  // 2048 f32 per-block loss partials

// shared byte-layout (28800 B total -> 5 blocks/CU):
//  qb fp8 [20][50][8] @0      (8000 B)   } overlaid first by x bf16 [50][272B-rows] @0 (13600 B)
//  kb fp8 [20][50][8] @8000   (8000 B)   } then by attnbuf bf16 [50][272] @0, logits f32 [50][68] @0
//  vtb bf16 [20][5][64] @16000 (12800 B) } h bf16 [50][272] @13600 (13600 B) after vtb dies
#define KB8 8000
#define VTB 16000
#define HB  13600
#define XROW 272                         // x/attn/h row stride in BYTES

__global__ __launch_bounds__(256) void prep_kernel(
    const float* __restrict__ Wk, const float* __restrict__ Wq,
    const float* __restrict__ Wv, const float* __restrict__ Wff,
    const float* __restrict__ Wlm, char* __restrict__ ws)
{
    int g = blockIdx.x * 256 + threadIdx.x;
    __hip_bfloat16* wkqv = (__hip_bfloat16*)(ws + WS_WKQV);
    __hip_bfloat16* wff  = (__hip_bfloat16*)(ws + WS_WFF);
    __hip_bfloat16* wlm  = (__hip_bfloat16*)(ws + WS_WLM);
    if (g < 40960) {
        int n = g >> 7, e = g & 127;
        float v = 0.f;
        if (e < Ee) {
            // sqrt(10*log2e) into BOTH k and q so fp8 sees balanced ranges
            if (n < 100)      v = Wk[n * Ee + e] * 3.7982825f;
            else if (n < 200) v = Wq[(n - 100) * Ee + e] * 3.7982825f;
            else if (n < 300) v = Wv[(n - 200) * Ee + e];
        }
        wkqv[g] = __float2bfloat16(v);
    } else if (g < 57344) {
        int gg = g - 40960; int n = gg >> 7, e = gg & 127;
        float v = (e < Ee && n < Ee) ? Wff[n * Ee + e] : 0.f;
        wff[gg] = __float2bfloat16(v);
    } else {
        int gg = g - 57344; int n = gg >> 7, e = gg & 127;
        float v = (e < Ee && n < Vv) ? Wlm[n * Ee + e] : 0.f;
        wlm[gg] = __float2bfloat16(v);
    }
}

__global__ __launch_bounds__(256, 5) void gpt_main(
    const int* __restrict__ idx, const int* __restrict__ targets,
    const float* __restrict__ tok_emb, const float* __restrict__ pos_emb,
    const float* __restrict__ b_ff, const float* __restrict__ b_lm,
    const char* __restrict__ ws, float* __restrict__ out,
    float* __restrict__ loss_part)
{
    __shared__ __attribute__((aligned(16))) unsigned char shB[28800];
    __shared__ int tok_s[Tt];
    __shared__ float bsum;

    const int b    = blockIdx.x;
    const int tid  = threadIdx.x;
    const int wave = tid >> 6;
    const int ln   = tid & 15;
    const int quad = (tid >> 4) & 3;

    // ---- P1: stage idx; zero ALL of shB; fill x = tok_emb[idx]+pos_emb (bf16) ----
    if (tid < Tt) tok_s[tid] = idx[b * Tt + tid];
    if (tid == 0) bsum = 0.f;
    {
        const uint4 z4 = make_uint4(0u, 0u, 0u, 0u);
        for (int i = tid; i < 1800; i += 256) ((uint4*)shB)[i] = z4;
    }
    __syncthreads();
    for (int i = tid; i < Tt * 25; i += 256) {
        int r = i / 25, c4 = (i - r * 25) * 4;
        const float4 te = *(const float4*)&tok_emb[tok_s[r] * Ee + c4];
        const float4 pe = *(const float4*)&pos_emb[r * Ee + c4];
        ushort4 o;
        o.x = bfbits(te.x + pe.x); o.y = bfbits(te.y + pe.y);
        o.z = bfbits(te.z + pe.z); o.w = bfbits(te.w + pe.w);
        *(ushort4*)&shB[r * XROW + c4 * 2] = o;
    }
    __syncthreads();

    // ---- P2: kqv = x @ Wkqv^T via MFMA (4 waves x 5 n-tiles x 4 m-tiles) ----
    {
        const __hip_bfloat16* wkqv = (const __hip_bfloat16*)(ws + WS_WKQV);
        f32x4 acc[5][4];
#pragma unroll
        for (int j = 0; j < 5; ++j)
#pragma unroll
            for (int mt = 0; mt < 4; ++mt) {
                f32x4 z = {0.f, 0.f, 0.f, 0.f};
                acc[j][mt] = z;
            }
#pragma unroll
        for (int kt = 0; kt < 4; ++kt) {
            v8bf a[4];
#pragma unroll
            for (int mt = 0; mt < 4; ++mt)
                a[mt] = (mt < 3 || ln < 2)
                      ? *(const v8bf*)&shB[(mt * 16 + ln) * XROW + (kt * 32 + quad * 8) * 2]
                      : bzero8();
#pragma unroll
            for (int j = 0; j < 5; ++j) {
                int nt = wave * 5 + j;
                v8bf bfr = *(const v8bf*)&wkqv[(nt * 16 + ln) * 128 + kt * 32 + quad * 8];
#pragma unroll
                for (int mt = 0; mt < 4; ++mt)
                    acc[j][mt] = __builtin_amdgcn_mfma_f32_16x16x32_bf16(a[mt], bfr, acc[j][mt], 0, 0, 0);
            }
        }
        __syncthreads();   // all x reads done; qb/kb overlay region becomes live
        // re-zero q/k row pads (bytes 5..7 of each 8-byte row) — stale x bytes otherwise
        for (int i = tid; i < 1000; i += 256) {
            shB[i * 8 + 5] = 0; *(unsigned short*)&shB[i * 8 + 6] = 0;
            shB[KB8 + i * 8 + 5] = 0; *(unsigned short*)&shB[KB8 + i * 8 + 6] = 0;
        }
        // C/D: col(n)=ln, row(m)=quad*4+r
#pragma unroll
        for (int j = 0; j < 5; ++j) {
            int n = (wave * 5 + j) * 16 + ln;
            if (n < 300) {
                int mat = n / 100;
                int jj  = n - mat * 100;
                int h   = jj / 5, d = jj - (jj / 5) * 5;
#pragma unroll
                for (int mt = 0; mt < 4; ++mt)
#pragma unroll
                    for (int r = 0; r < 4; ++r) {
                        int m = mt * 16 + quad * 4 + r;
                        if (m < Tt) {
                            float v = acc[j][mt][r];
                            if (mat == 0)      shB[KB8 + (h * 50 + m) * 8 + d] = f32_to_fp8(v);
                            else if (mat == 1) shB[(h * 50 + m) * 8 + d] = f32_to_fp8(v);
                            else *(unsigned short*)&shB[VTB + ((h * 5 + d) * 64 + m) * 2] = bfbits(v);
                        }
                    }
            }
        }
    }
    __syncthreads();

    // ---- P3: attention in-register; q/k fragments are fp8 (one b64 per frag).
    //  Orientation-2 (A=k,B=q): D2[t][s] -> masked exp -> tile-sum -> ones-MFMA
    //  puts denom[s] at PV-B lane/reg coords -> rd folds into v-fragment.
    //  Orientation-1 (A=q,B=k): D1[s][t] -> masked exp = PV A-frag directly.
    //  NaN garbage from OOB rows (t,s>=50) always lands in masked lanes/regs. ----
    unsigned attp[5][8];
    {
        v4s ones4; ones4[0] = ones4[1] = ones4[2] = ones4[3] = (short)0x3F80; // bf16 1.0
#pragma unroll
        for (int hj = 0; hj < 5; ++hj) {
            const int h = wave * 5 + hj;
            long qf[4], kf[4];
#pragma unroll
            for (int i = 0; i < 4; ++i) {
                int row = i * 16 + ln;
                qf[i] = (quad == 0) ? *(const long*)&shB[(h * 50 + row) * 8] : 0L;
                kf[i] = (quad == 0) ? *(const long*)&shB[KB8 + (h * 50 + row) * 8] : 0L;
            }
            // --- denominators ---
            float rdv[4][4];
#pragma unroll
            for (int ns = 0; ns < 4; ++ns) {
                float esum[4] = {0.f, 0.f, 0.f, 0.f};
#pragma unroll
                for (int mt = ns; mt < 4; ++mt) {
                    f32x4 z = {0.f, 0.f, 0.f, 0.f};
                    f32x4 t2 = __builtin_amdgcn_mfma_f32_16x16x32_fp8_fp8(kf[mt], qf[ns], z, 0, 0, 0);
                    int s = ns * 16 + ln;
#pragma unroll
                    for (int r = 0; r < 4; ++r) {
                        int t = mt * 16 + quad * 4 + r;
                        float x = __builtin_amdgcn_exp2f(t2[r]);
                        esum[r] += (t >= s && t < Tt && s < Tt) ? x : 0.f;
                    }
                }
                v4s af;
                af[0] = (short)bfbits(esum[0]); af[1] = (short)bfbits(esum[1]);
                af[2] = (short)bfbits(esum[2]); af[3] = (short)bfbits(esum[3]);
                f32x4 z = {0.f, 0.f, 0.f, 0.f};
                f32x4 dres = mfma_16x16x16_bf16(af, ones4, z);
#pragma unroll
                for (int r = 0; r < 4; ++r) {
                    int s = ns * 16 + quad * 4 + r;
                    rdv[ns][r] = (s < Tt) ? __builtin_amdgcn_rcpf(dres[r]) : 0.f;
                }
            }
            // --- PV ---
            f32x4 pac[4];
#pragma unroll
            for (int mt = 0; mt < 4; ++mt) { f32x4 z = {0.f, 0.f, 0.f, 0.f}; pac[mt] = z; }
#pragma unroll
            for (int ms = 0; ms < 4; ++ms) {
                v4s braw;
                if (ln < Dd) braw = *(const v4s*)&shB[VTB + ((h * 5 + ln) * 64 + ms * 16 + quad * 4) * 2];
                else { v4s z = {0, 0, 0, 0}; braw = z; }
                v4s bvt;
#pragma unroll
                for (int j = 0; j < 4; ++j)
                    bvt[j] = (short)bfbits(bf2f(braw[j]) * rdv[ms][j]);
#pragma unroll
                for (int u = 0; u < 4 - ms; ++u) {
                    f32x4 z = {0.f, 0.f, 0.f, 0.f};
                    f32x4 t1 = __builtin_amdgcn_mfma_f32_16x16x32_fp8_fp8(qf[ms], kf[ms + u], z, 0, 0, 0);
                    int t = (ms + u) * 16 + ln;
                    v4s af;
#pragma unroll
                    for (int r = 0; r < 4; ++r) {
                        int s = ms * 16 + quad * 4 + r;
                        float x = __builtin_amdgcn_exp2f(t1[r]);
                        x = (t >= s && t < Tt && s < Tt) ? x : 0.f;
                        af[r] = (short)bfbits(x);
                    }
                    pac[ms + u] = mfma_16x16x16_bf16(af, bvt, pac[ms + u]);
                }
            }
            // C/D of 16x16x16: col n=ln (d), row m=quad*4+r -> t = mt*16+quad*4+r
#pragma unroll
            for (int mt = 0; mt < 4; ++mt) {
                attp[hj][mt * 2]     = pack2(pac[mt][0], pac[mt][1]);
                attp[hj][mt * 2 + 1] = pack2(pac[mt][2], pac[mt][3]);
            }
        }
    }
    __syncthreads();   // all qb/kb/vtb reads done; region becomes attnbuf

    // ---- dump attn registers -> attnbuf (bf16 [50] rows @0) ----
#pragma unroll
    for (int hj = 0; hj < 5; ++hj) {
        int col = (wave * 5 + hj) * 5 + ln;
#pragma unroll
        for (int mt = 0; mt < 4; ++mt)
#pragma unroll
            for (int r = 0; r < 4; ++r) {
                int t = mt * 16 + quad * 4 + r;
                if (ln < Dd && t < Tt) {
                    unsigned w = attp[hj][mt * 2 + (r >> 1)];
                    unsigned short v = (unsigned short)((r & 1) ? (w >> 16) : (w & 0xffff));
                    *(unsigned short*)&shB[t * XROW + col * 2] = v;
                }
            }
    }
    __syncthreads();

    // ---- P4: h = relu(attn @ Wff^T + b_ff); attnbuf@0 -> h@HB ----
    {
        const __hip_bfloat16* wff = (const __hip_bfloat16*)(ws + WS_WFF);
        f32x4 fac[2][4];
#pragma unroll
        for (int u = 0; u < 2; ++u)
#pragma unroll
            for (int mt = 0; mt < 4; ++mt) {
                f32x4 z = {0.f, 0.f, 0.f, 0.f};
                fac[u][mt] = z;
            }
        const int nn = (wave < 3) ? 2 : 1;
#pragma unroll
        for (int kt = 0; kt < 4; ++kt) {
            v8bf a[4];
#pragma unroll
            for (int mt = 0; mt < 4; ++mt)
                a[mt] = (mt < 3 || ln < 2)
                      ? *(const v8bf*)&shB[(mt * 16 + ln) * XROW + (kt * 32 + quad * 8) * 2]
                      : bzero8();
#pragma unroll
            for (int u = 0; u < 2; ++u) {
                if (u < nn) {
                    int nt = wave + u * 4;
                    v8bf bfr = *(const v8bf*)&wff[(nt * 16 + ln) * 128 + kt * 32 + quad * 8];
#pragma unroll
                    for (int mt = 0; mt < 4; ++mt)
                        fac[u][mt] = __builtin_amdgcn_mfma_f32_16x16x32_bf16(a[mt], bfr, fac[u][mt], 0, 0, 0);
                }
            }
        }
#pragma unroll
        for (int u = 0; u < 2; ++u) {
            if (u < nn) {
                int n = (wave + u * 4) * 16 + ln;
                if (n < Ee) {
                    float bias = b_ff[n];
#pragma unroll
                    for (int mt = 0; mt < 4; ++mt)
#pragma unroll
                        for (int r = 0; r < 4; ++r) {
                            int m = mt * 16 + quad * 4 + r;
                            if (m < Tt) {
                                float v = fac[u][mt][r] + bias;
                                *(unsigned short*)&shB[HB + m * XROW + n * 2] =
                                    bfbits(v > 0.f ? v : 0.f);
                            }
                        }
                }
            }
        }
    }
    __syncthreads();

    // ---- P5: logits = h @ Wlm^T + b_lm; h@HB -> out (f32) + logits f32 @0 ----
    {
        const __hip_bfloat16* wlm = (const __hip_bfloat16*)(ws + WS_WLM);
        float* lgl = (float*)shB;   // [50][68] f32 = 13600B
#pragma unroll
        for (int i = 0; i < 5; ++i) {
            int job = wave + i * 4;            // 0..19
            int mt = job / 5, nt = job - (job / 5) * 5;
            f32x4 acc = {0.f, 0.f, 0.f, 0.f};
#pragma unroll
            for (int kt = 0; kt < 4; ++kt) {
                v8bf a = (mt < 3 || ln < 2)
                       ? *(const v8bf*)&shB[HB + (mt * 16 + ln) * XROW + (kt * 32 + quad * 8) * 2]
                       : bzero8();
                v8bf bf = *(const v8bf*)&wlm[(nt * 16 + ln) * 128 + kt * 32 + quad * 8];
                acc = __builtin_amdgcn_mfma_f32_16x16x32_bf16(a, bf, acc, 0, 0, 0);
            }
            int n = nt * 16 + ln;
            if (n < Vv) {
                float bias = b_lm[n];
#pragma unroll
                for (int r = 0; r < 4; ++r) {
                    int m = mt * 16 + quad * 4 + r;
                    if (m < Tt) {
                        float v = acc[r] + bias;
                        out[(b * Tt + m) * Vv + n] = v;
                        lgl[m * 68 + n] = v;
                    }
                }
            }
        }
    }
    __syncthreads();

    // ---- P6: loss; 4 lanes per token row; per-block partial -> ws array ----
    if (tid < 200) {
        int r = tid >> 2, lv = tid & 3;
        const float* row = (const float*)shB + r * 68;
        float mx = -3.0e38f;
        for (int v = lv; v < Vv; v += 4) mx = fmaxf(mx, row[v]);
        mx = fmaxf(mx, __shfl_xor(mx, 1));
        mx = fmaxf(mx, __shfl_xor(mx, 2));
        float sum = 0.f;
        for (int v = lv; v < Vv; v += 4)
            sum += __builtin_amdgcn_exp2f((row[v] - mx) * 1.4426950408889634f);
        sum += __shfl_xor(sum, 1);
        sum += __shfl_xor(sum, 2);
        if (lv == 0) {
            float lse = mx + 0.69314718055994531f * log2f(sum);
            int tgt = targets[b * Tt + r];
            atomicAdd(&bsum, lse - row[tgt]);
        }
    }
    __syncthreads();
    if (tid == 0) loss_part[b] = bsum;   // plain store; no global atomics
}

__global__ __launch_bounds__(256) void loss_reduce(const float* __restrict__ lp,
                                                   float* __restrict__ out)
{
    __shared__ float wsum[4];
    int tid = threadIdx.x;
    float s = 0.f;
    for (int i = tid; i < Bb; i += 256) s += lp[i];
    s += __shfl_xor(s, 1);  s += __shfl_xor(s, 2);  s += __shfl_xor(s, 4);
    s += __shfl_xor(s, 8);  s += __shfl_xor(s, 16); s += __shfl_xor(s, 32);
    if ((tid & 63) == 0) wsum[tid >> 6] = s;
    __syncthreads();
    if (tid == 0)
        out[Bb * Tt * Vv] = (wsum[0] + wsum[1] + wsum[2] + wsum[3]) * (1.0f / (float)(Bb * Tt));
}

extern "C" void kernel_launch(void* const* d_in, const int* in_sizes, int n_in,
                              void* d_out, int out_size, void* d_ws, size_t ws_size,
                              hipStream_t stream)
{
    const int* idx     = (const int*)d_in[0];
    const int* targets = (const int*)d_in[1];
    const float* tok_emb = (const float*)d_in[2];
    const float* pos_emb = (const float*)d_in[3];
    const float* Wk  = (const float*)d_in[4];
    const float* Wq  = (const float*)d_in[5];
    const float* Wv  = (const float*)d_in[6];
    const float* Wff = (const float*)d_in[7];
    const float* bff = (const float*)d_in[8];
    const float* Wlm = (const float*)d_in[9];
    const float* blm = (const float*)d_in[10];
    float* out = (float*)d_out;
    char* ws = (char*)d_ws;
    float* loss_part = (float*)(ws + WS_LPART);

    hipLaunchKernelGGL(prep_kernel, dim3(264), dim3(256), 0, stream, Wk, Wq, Wv, Wff, Wlm, ws);
    hipLaunchKernelGGL(gpt_main, dim3(Bb), dim3(256), 0, stream,
                       idx, targets, tok_emb, pos_emb, bff, blm, (const char*)ws, out, loss_part);
    hipLaunchKernelGGL(loss_reduce, dim3(1), dim3(256), 0, stream, loss_part, out);
}

// Round 10
// 193.345 us; speedup vs baseline: 1.2491x; 1.2491x over previous
//
#include <hip/hip_runtime.h>
#include <hip/hip_bf16.h>
#include <hip/hip_fp8.h>

// Problem constants
#define Bb 2048
#define Tt 50
#define Vv 65
#define Ee 100
#define Hh 20
#define Dd 5

typedef __bf16 v8bf __attribute__((ext_vector_type(8)));
typedef short v8s __attribute__((ext_vector_type(8)));
typedef short v4s __attribute__((ext_vector_type(4)));
typedef float f32x4 __attribute__((ext_vector_type(4)));

__device__ __forceinline__ v8bf bzero8() {
    v8s z = {0, 0, 0, 0, 0, 0, 0, 0};
    union { v8s s; v8bf b; } u; u.s = z; return u.b;
}
__device__ __forceinline__ unsigned short bfbits(float f) {
    union { __hip_bfloat16 h; unsigned short s; } c;
    c.h = __float2bfloat16(f);
    return c.s;
}
__device__ __forceinline__ float bf2f(short s) {
    union { unsigned i; float f; } c; c.i = ((unsigned)(unsigned short)s) << 16; return c.f;
}
__device__ __forceinline__ unsigned pack2(float a, float b) {
    return (unsigned)bfbits(a) | ((unsigned)bfbits(b) << 16);
}
__device__ __forceinline__ unsigned char f32_to_fp8(float v) {
#if __has_builtin(__builtin_amdgcn_cvt_pk_fp8_f32)
    return (unsigned char)(__builtin_amdgcn_cvt_pk_fp8_f32(v, 0.f, 0, false) & 0xff);
#else
    union { __hip_fp8_e4m3 t; unsigned char c; } u;
    u.t = __hip_fp8_e4m3(v);
    return u.c;
#endif
}

// K=16 bf16 MFMA (validated on HW in R7/R8)
__device__ __forceinline__ f32x4 mfma_16x16x16_bf16(v4s a, v4s b, f32x4 c) {
#if __has_builtin(__builtin_amdgcn_mfma_f32_16x16x16bf16_1k)
    return __builtin_amdgcn_mfma_f32_16x16x16bf16_1k(a, b, c, 0, 0, 0);
#else
    f32x4 d;
    asm volatile("v_mfma_f32_16x16x16_bf16 %0, %1, %2, %3\n\ts_nop 7\n\ts_nop 4"
                 : "=v"(d) : "v"(a), "v"(b), "v"(c));
    return d;
#endif
}

// ws layout (bytes)
#define WS_WKQV 1024                     // [320][128] bf16 (k AND q rows pre-scaled by sqrt(10*log2e))
#define WS_WFF  (1024 + 81920)           // [128][128] bf16
#define WS_WLM  (1024 + 81920 + 32768)   // [80][128] bf16
#define WS_LPART (1024 + 81920 + 32768 + 20480)  // 2048 f32 per-block loss partials

// shared byte-layout (28800 B total -> 5 blocks/CU):
//  qb fp8 [20][50][8] @0      (8000 B)   } overlaid first by x bf16 [50][272B-rows] @0 (13600 B)
//  kb fp8 [20][50][8] @8000   (8000 B)   } then by attnbuf bf16 [50][272] @0, logits f32 [50][68] @0
//  vtb bf16 [20][5][64] @16000 (12800 B) } h bf16 [50][272] @13600 (13600 B) after vtb dies
#define KB8 8000
#define VTB 16000
#define HB  13600
#define XROW 272                         // x/attn/h row stride in BYTES

__global__ __launch_bounds__(256) void prep_kernel(
    const float* __restrict__ Wk, const float* __restrict__ Wq,
    const float* __restrict__ Wv, const float* __restrict__ Wff,
    const float* __restrict__ Wlm, char* __restrict__ ws)
{
    int g = blockIdx.x * 256 + threadIdx.x;
    __hip_bfloat16* wkqv = (__hip_bfloat16*)(ws + WS_WKQV);
    __hip_bfloat16* wff  = (__hip_bfloat16*)(ws + WS_WFF);
    __hip_bfloat16* wlm  = (__hip_bfloat16*)(ws + WS_WLM);
    if (g < 40960) {
        int n = g >> 7, e = g & 127;
        float v = 0.f;
        if (e < Ee) {
            // sqrt(10*log2e) into BOTH k and q so fp8 sees balanced ranges
            if (n < 100)      v = Wk[n * Ee + e] * 3.7982825f;
            else if (n < 200) v = Wq[(n - 100) * Ee + e] * 3.7982825f;
            else if (n < 300) v = Wv[(n - 200) * Ee + e];
        }
        wkqv[g] = __float2bfloat16(v);
    } else if (g < 57344) {
        int gg = g - 40960; int n = gg >> 7, e = gg & 127;
        float v = (e < Ee && n < Ee) ? Wff[n * Ee + e] : 0.f;
        wff[gg] = __float2bfloat16(v);
    } else {
        int gg = g - 57344; int n = gg >> 7, e = gg & 127;
        float v = (e < Ee && n < Vv) ? Wlm[n * Ee + e] : 0.f;
        wlm[gg] = __float2bfloat16(v);
    }
}

// launch_bounds (256,4): VGPR cap 128 >= ~84 needed -> NO spills (R9's (256,5)
// capped at ~102 and the allocator spilled ~180KB/block to scratch: FETCH 113MB,
// WRITE 279MB). Occupancy comes from LDS: 28.8KB -> 5 blocks/CU at runtime.
__global__ __launch_bounds__(256, 4) void gpt_main(
    const int* __restrict__ idx, const int* __restrict__ targets,
    const float* __restrict__ tok_emb, const float* __restrict__ pos_emb,
    const float* __restrict__ b_ff, const float* __restrict__ b_lm,
    const char* __restrict__ ws, float* __restrict__ out,
    float* __restrict__ loss_part)
{
    __shared__ __attribute__((aligned(16))) unsigned char shB[28800];
    __shared__ int tok_s[Tt];
    __shared__ float bsum;

    const int b    = blockIdx.x;
    const int tid  = threadIdx.x;
    const int wave = tid >> 6;
    const int ln   = tid & 15;
    const int quad = (tid >> 4) & 3;

    // ---- P1: stage idx; zero ALL of shB; fill x = tok_emb[idx]+pos_emb (bf16) ----
    if (tid < Tt) tok_s[tid] = idx[b * Tt + tid];
    if (tid == 0) bsum = 0.f;
    {
        const uint4 z4 = make_uint4(0u, 0u, 0u, 0u);
        for (int i = tid; i < 1800; i += 256) ((uint4*)shB)[i] = z4;
    }
    __syncthreads();
    for (int i = tid; i < Tt * 25; i += 256) {
        int r = i / 25, c4 = (i - r * 25) * 4;
        const float4 te = *(const float4*)&tok_emb[tok_s[r] * Ee + c4];
        const float4 pe = *(const float4*)&pos_emb[r * Ee + c4];
        ushort4 o;
        o.x = bfbits(te.x + pe.x); o.y = bfbits(te.y + pe.y);
        o.z = bfbits(te.z + pe.z); o.w = bfbits(te.w + pe.w);
        *(ushort4*)&shB[r * XROW + c4 * 2] = o;
    }
    __syncthreads();

    // ---- P2: kqv = x @ Wkqv^T via MFMA (4 waves x 5 n-tiles x 4 m-tiles) ----
    {
        const __hip_bfloat16* wkqv = (const __hip_bfloat16*)(ws + WS_WKQV);
        f32x4 acc[5][4];
#pragma unroll
        for (int j = 0; j < 5; ++j)
#pragma unroll
            for (int mt = 0; mt < 4; ++mt) {
                f32x4 z = {0.f, 0.f, 0.f, 0.f};
                acc[j][mt] = z;
            }
#pragma unroll
        for (int kt = 0; kt < 4; ++kt) {
            v8bf a[4];
#pragma unroll
            for (int mt = 0; mt < 4; ++mt)
                a[mt] = (mt < 3 || ln < 2)
                      ? *(const v8bf*)&shB[(mt * 16 + ln) * XROW + (kt * 32 + quad * 8) * 2]
                      : bzero8();
#pragma unroll
            for (int j = 0; j < 5; ++j) {
                int nt = wave * 5 + j;
                v8bf bfr = *(const v8bf*)&wkqv[(nt * 16 + ln) * 128 + kt * 32 + quad * 8];
#pragma unroll
                for (int mt = 0; mt < 4; ++mt)
                    acc[j][mt] = __builtin_amdgcn_mfma_f32_16x16x32_bf16(a[mt], bfr, acc[j][mt], 0, 0, 0);
            }
        }
        __syncthreads();   // all x reads done; qb/kb overlay region becomes live
        // re-zero q/k row pads (bytes 5..7 of each 8-byte row) — stale x bytes otherwise
        for (int i = tid; i < 1000; i += 256) {
            shB[i * 8 + 5] = 0; *(unsigned short*)&shB[i * 8 + 6] = 0;
            shB[KB8 + i * 8 + 5] = 0; *(unsigned short*)&shB[KB8 + i * 8 + 6] = 0;
        }
        // C/D: col(n)=ln, row(m)=quad*4+r
#pragma unroll
        for (int j = 0; j < 5; ++j) {
            int n = (wave * 5 + j) * 16 + ln;
            if (n < 300) {
                int mat = n / 100;
                int jj  = n - mat * 100;
                int h   = jj / 5, d = jj - (jj / 5) * 5;
#pragma unroll
                for (int mt = 0; mt < 4; ++mt)
#pragma unroll
                    for (int r = 0; r < 4; ++r) {
                        int m = mt * 16 + quad * 4 + r;
                        if (m < Tt) {
                            float v = acc[j][mt][r];
                            if (mat == 0)      shB[KB8 + (h * 50 + m) * 8 + d] = f32_to_fp8(v);
                            else if (mat == 1) shB[(h * 50 + m) * 8 + d] = f32_to_fp8(v);
                            else *(unsigned short*)&shB[VTB + ((h * 5 + d) * 64 + m) * 2] = bfbits(v);
                        }
                    }
            }
        }
    }
    __syncthreads();

    // ---- P3: attention in-register; q/k fragments are fp8 (one b64 per frag).
    //  Orientation-2 (A=k,B=q): D2[t][s] -> masked exp -> tile-sum -> ones-MFMA
    //  puts denom[s] at PV-B lane/reg coords -> rd folds into v-fragment.
    //  Orientation-1 (A=q,B=k): D1[s][t] -> masked exp = PV A-frag directly.
    //  NaN garbage from OOB rows (t,s>=50) always lands in masked lanes/regs. ----
    unsigned attp[5][8];
    {
        v4s ones4; ones4[0] = ones4[1] = ones4[2] = ones4[3] = (short)0x3F80; // bf16 1.0
#pragma unroll
        for (int hj = 0; hj < 5; ++hj) {
            const int h = wave * 5 + hj;
            long qf[4], kf[4];
#pragma unroll
            for (int i = 0; i < 4; ++i) {
                int row = i * 16 + ln;
                qf[i] = (quad == 0) ? *(const long*)&shB[(h * 50 + row) * 8] : 0L;
                kf[i] = (quad == 0) ? *(const long*)&shB[KB8 + (h * 50 + row) * 8] : 0L;
            }
            // --- denominators ---
            float rdv[4][4];
#pragma unroll
            for (int ns = 0; ns < 4; ++ns) {
                float esum[4] = {0.f, 0.f, 0.f, 0.f};
#pragma unroll
                for (int mt = ns; mt < 4; ++mt) {
                    f32x4 z = {0.f, 0.f, 0.f, 0.f};
                    f32x4 t2 = __builtin_amdgcn_mfma_f32_16x16x32_fp8_fp8(kf[mt], qf[ns], z, 0, 0, 0);
                    int s = ns * 16 + ln;
#pragma unroll
                    for (int r = 0; r < 4; ++r) {
                        int t = mt * 16 + quad * 4 + r;
                        float x = __builtin_amdgcn_exp2f(t2[r]);
                        esum[r] += (t >= s && t < Tt && s < Tt) ? x : 0.f;
                    }
                }
                v4s af;
                af[0] = (short)bfbits(esum[0]); af[1] = (short)bfbits(esum[1]);
                af[2] = (short)bfbits(esum[2]); af[3] = (short)bfbits(esum[3]);
                f32x4 z = {0.f, 0.f, 0.f, 0.f};
                f32x4 dres = mfma_16x16x16_bf16(af, ones4, z);
#pragma unroll
                for (int r = 0; r < 4; ++r) {
                    int s = ns * 16 + quad * 4 + r;
                    rdv[ns][r] = (s < Tt) ? __builtin_amdgcn_rcpf(dres[r]) : 0.f;
                }
            }
            // --- PV ---
            f32x4 pac[4];
#pragma unroll
            for (int mt = 0; mt < 4; ++mt) { f32x4 z = {0.f, 0.f, 0.f, 0.f}; pac[mt] = z; }
#pragma unroll
            for (int ms = 0; ms < 4; ++ms) {
                v4s braw;
                if (ln < Dd) braw = *(const v4s*)&shB[VTB + ((h * 5 + ln) * 64 + ms * 16 + quad * 4) * 2];
                else { v4s z = {0, 0, 0, 0}; braw = z; }
                v4s bvt;
#pragma unroll
                for (int j = 0; j < 4; ++j)
                    bvt[j] = (short)bfbits(bf2f(braw[j]) * rdv[ms][j]);
#pragma unroll
                for (int u = 0; u < 4 - ms; ++u) {
                    f32x4 z = {0.f, 0.f, 0.f, 0.f};
                    f32x4 t1 = __builtin_amdgcn_mfma_f32_16x16x32_fp8_fp8(qf[ms], kf[ms + u], z, 0, 0, 0);
                    int t = (ms + u) * 16 + ln;
                    v4s af;
#pragma unroll
                    for (int r = 0; r < 4; ++r) {
                        int s = ms * 16 + quad * 4 + r;
                        float x = __builtin_amdgcn_exp2f(t1[r]);
                        x = (t >= s && t < Tt && s < Tt) ? x : 0.f;
                        af[r] = (short)bfbits(x);
                    }
                    pac[ms + u] = mfma_16x16x16_bf16(af, bvt, pac[ms + u]);
                }
            }
            // C/D of 16x16x16: col n=ln (d), row m=quad*4+r -> t = mt*16+quad*4+r
#pragma unroll
            for (int mt = 0; mt < 4; ++mt) {
                attp[hj][mt * 2]     = pack2(pac[mt][0], pac[mt][1]);
                attp[hj][mt * 2 + 1] = pack2(pac[mt][2], pac[mt][3]);
            }
        }
    }
    __syncthreads();   // all qb/kb/vtb reads done; region becomes attnbuf

    // ---- dump attn registers -> attnbuf (bf16 [50] rows @0) ----
#pragma unroll
    for (int hj = 0; hj < 5; ++hj) {
        int col = (wave * 5 + hj) * 5 + ln;
#pragma unroll
        for (int mt = 0; mt < 4; ++mt)
#pragma unroll
            for (int r = 0; r < 4; ++r) {
                int t = mt * 16 + quad * 4 + r;
                if (ln < Dd && t < Tt) {
                    unsigned w = attp[hj][mt * 2 + (r >> 1)];
                    unsigned short v = (unsigned short)((r & 1) ? (w >> 16) : (w & 0xffff));
                    *(unsigned short*)&shB[t * XROW + col * 2] = v;
                }
            }
    }
    __syncthreads();

    // ---- P4: h = relu(attn @ Wff^T + b_ff); attnbuf@0 -> h@HB ----
    {
        const __hip_bfloat16* wff = (const __hip_bfloat16*)(ws + WS_WFF);
        f32x4 fac[2][4];
#pragma unroll
        for (int u = 0; u < 2; ++u)
#pragma unroll
            for (int mt = 0; mt < 4; ++mt) {
                f32x4 z = {0.f, 0.f, 0.f, 0.f};
                fac[u][mt] = z;
            }
        const int nn = (wave < 3) ? 2 : 1;
#pragma unroll
        for (int kt = 0; kt < 4; ++kt) {
            v8bf a[4];
#pragma unroll
            for (int mt = 0; mt < 4; ++mt)
                a[mt] = (mt < 3 || ln < 2)
                      ? *(const v8bf*)&shB[(mt * 16 + ln) * XROW + (kt * 32 + quad * 8) * 2]
                      : bzero8();
#pragma unroll
            for (int u = 0; u < 2; ++u) {
                if (u < nn) {
                    int nt = wave + u * 4;
                    v8bf bfr = *(const v8bf*)&wff[(nt * 16 + ln) * 128 + kt * 32 + quad * 8];
#pragma unroll
                    for (int mt = 0; mt < 4; ++mt)
                        fac[u][mt] = __builtin_amdgcn_mfma_f32_16x16x32_bf16(a[mt], bfr, fac[u][mt], 0, 0, 0);
                }
            }
        }
#pragma unroll
        for (int u = 0; u < 2; ++u) {
            if (u < nn) {
                int n = (wave + u * 4) * 16 + ln;
                if (n < Ee) {
                    float bias = b_ff[n];
#pragma unroll
                    for (int mt = 0; mt < 4; ++mt)
#pragma unroll
                        for (int r = 0; r < 4; ++r) {
                            int m = mt * 16 + quad * 4 + r;
                            if (m < Tt) {
                                float v = fac[u][mt][r] + bias;
                                *(unsigned short*)&shB[HB + m * XROW + n * 2] =
                                    bfbits(v > 0.f ? v : 0.f);
                            }
                        }
                }
            }
        }
    }
    __syncthreads();

    // ---- P5: logits = h @ Wlm^T + b_lm; h@HB -> out (f32) + logits f32 @0 ----
    {
        const __hip_bfloat16* wlm = (const __hip_bfloat16*)(ws + WS_WLM);
        float* lgl = (float*)shB;   // [50][68] f32 = 13600B
#pragma unroll
        for (int i = 0; i < 5; ++i) {
            int job = wave + i * 4;            // 0..19
            int mt = job / 5, nt = job - (job / 5) * 5;
            f32x4 acc = {0.f, 0.f, 0.f, 0.f};
#pragma unroll
            for (int kt = 0; kt < 4; ++kt) {
                v8bf a = (mt < 3 || ln < 2)
                       ? *(const v8bf*)&shB[HB + (mt * 16 + ln) * XROW + (kt * 32 + quad * 8) * 2]
                       : bzero8();
                v8bf bf = *(const v8bf*)&wlm[(nt * 16 + ln) * 128 + kt * 32 + quad * 8];
                acc = __builtin_amdgcn_mfma_f32_16x16x32_bf16(a, bf, acc, 0, 0, 0);
            }
            int n = nt * 16 + ln;
            if (n < Vv) {
                float bias = b_lm[n];
#pragma unroll
                for (int r = 0; r < 4; ++r) {
                    int m = mt * 16 + quad * 4 + r;
                    if (m < Tt) {
                        float v = acc[r] + bias;
                        out[(b * Tt + m) * Vv + n] = v;
                        lgl[m * 68 + n] = v;
                    }
                }
            }
        }
    }
    __syncthreads();

    // ---- P6: loss; 4 lanes per token row; per-block partial -> ws array ----
    if (tid < 200) {
        int r = tid >> 2, lv = tid & 3;
        const float* row = (const float*)shB + r * 68;
        float mx = -3.0e38f;
        for (int v = lv; v < Vv; v += 4) mx = fmaxf(mx, row[v]);
        mx = fmaxf(mx, __shfl_xor(mx, 1));
        mx = fmaxf(mx, __shfl_xor(mx, 2));
        float sum = 0.f;
        for (int v = lv; v < Vv; v += 4)
            sum += __builtin_amdgcn_exp2f((row[v] - mx) * 1.4426950408889634f);
        sum += __shfl_xor(sum, 1);
        sum += __shfl_xor(sum, 2);
        if (lv == 0) {
            float lse = mx + 0.69314718055994531f * log2f(sum);
            int tgt = targets[b * Tt + r];
            atomicAdd(&bsum, lse - row[tgt]);
        }
    }
    __syncthreads();
    if (tid == 0) loss_part[b] = bsum;   // plain store; no global atomics
}

__global__ __launch_bounds__(256) void loss_reduce(const float* __restrict__ lp,
                                                   float* __restrict__ out)
{
    __shared__ float wsum[4];
    int tid = threadIdx.x;
    float s = 0.f;
    for (int i = tid; i < Bb; i += 256) s += lp[i];
    s += __shfl_xor(s, 1);  s += __shfl_xor(s, 2);  s += __shfl_xor(s, 4);
    s += __shfl_xor(s, 8);  s += __shfl_xor(s, 16); s += __shfl_xor(s, 32);
    if ((tid & 63) == 0) wsum[tid >> 6] = s;
    __syncthreads();
    if (tid == 0)
        out[Bb * Tt * Vv] = (wsum[0] + wsum[1] + wsum[2] + wsum[3]) * (1.0f / (float)(Bb * Tt));
}

extern "C" void kernel_launch(void* const* d_in, const int* in_sizes, int n_in,
                              void* d_out, int out_size, void* d_ws, size_t ws_size,
                              hipStream_t stream)
{
    const int* idx     = (const int*)d_in[0];
    const int* targets = (const int*)d_in[1];
    const float* tok_emb = (const float*)d_in[2];
    const float* pos_emb = (const float*)d_in[3];
    const float* Wk  = (const float*)d_in[4];
    const float* Wq  = (const float*)d_in[5];
    const float* Wv  = (const float*)d_in[6];
    const float* Wff = (const float*)d_in[7];
    const float* bff = (const float*)d_in[8];
    const float* Wlm = (const float*)d_in[9];
    const float* blm = (const float*)d_in[10];
    float* out = (float*)d_out;
    char* ws = (char*)d_ws;
    float* loss_part = (float*)(ws + WS_LPART);

    hipLaunchKernelGGL(prep_kernel, dim3(264), dim3(256), 0, stream, Wk, Wq, Wv, Wff, Wlm, ws);
    hipLaunchKernelGGL(gpt_main, dim3(Bb), dim3(256), 0, stream,
                       idx, targets, tok_emb, pos_emb, bff, blm, (const char*)ws, out, loss_part);
    hipLaunchKernelGGL(loss_reduce, dim3(1), dim3(256), 0, stream, loss_part, out);
}